// Round 1
// baseline (6700.868 us; speedup 1.0000x reference)
//
#include <hip/hip_runtime.h>
#include <math.h>

#define NB    32
#define NHW   32
#define NC    128
#define NTOT  (NB*NHW*NHW*NC)     // 4194304
#define N4    (NTOT/4)

// state layout: st[0]=t, st[1]=dt, st[2]=dt_c, st[3]=done, st[4]=adv

__global__ __launch_bounds__(64) void init_kernel(float* __restrict__ st, double* __restrict__ acc)
{
    int i = threadIdx.x;
    if (i < 32) acc[i] = 0.0;
    if (i == 0) { st[0]=0.0f; st[1]=0.05f; st[2]=0.05f; st[3]=0.0f; st[4]=0.0f; }
}

__global__ __launch_bounds__(256) void copy_kernel(float* __restrict__ dst, const float* __restrict__ src)
{
    int stride = gridDim.x * blockDim.x;
    for (int i = blockIdx.x*blockDim.x + threadIdx.x; i < N4; i += stride)
        reinterpret_cast<float4*>(dst)[i] = reinterpret_cast<const float4*>(src)[i];
}

__global__ __launch_bounds__(256) void copy_if_adv_kernel(float* __restrict__ dst,
                                                          const float* __restrict__ src,
                                                          const float* __restrict__ st)
{
    if (st[4] == 0.0f) return;
    int stride = gridDim.x * blockDim.x;
    for (int i = blockIdx.x*blockDim.x + threadIdx.x; i < N4; i += stride)
        reinterpret_cast<float4*>(dst)[i] = reinterpret_cast<const float4*>(src)[i];
}

// Direct conv 3x3 SAME, 128(+t)->128 channels, fused bias+relu and constant-t
// extra input channel (channel index 128 of w). One block: 8x8 spatial tile,
// all 128 cout, one batch image.
__global__ __launch_bounds__(256) void conv_relu_kernel(
    const float* __restrict__ in, const float* __restrict__ w,
    const float* __restrict__ bias, float* __restrict__ out,
    const float* __restrict__ st, float cfrac)
{
    if (st[3] != 0.0f) return;
    __shared__ float lds[10*10*128];
    const int b  = blockIdx.y;
    const int ty = (blockIdx.x >> 2) * 8;
    const int tx = (blockIdx.x & 3) * 8;
    const int tid = threadIdx.x;

    const float* inb = in + (size_t)b * (NHW*NHW*NC);
    for (int i = tid; i < 10*10*32; i += 256) {
        int c  = (i & 31) << 2;
        int s  = i >> 5;
        int sx = s % 10, sy = s / 10;
        int gy = ty + sy - 1, gx = tx + sx - 1;
        float4 v = make_float4(0.f,0.f,0.f,0.f);
        if ((unsigned)gy < 32u && (unsigned)gx < 32u)
            v = *reinterpret_cast<const float4*>(inb + ((gy*32 + gx)*128 + c));
        *reinterpret_cast<float4*>(&lds[(sy*10 + sx)*128 + c]) = v;
    }
    __syncthreads();

    const int co  = (tid & 31) << 2;   // 4 consecutive cout
    const int row = tid >> 5;          // 0..7 tile row

    float acc[8][4];
    #pragma unroll
    for (int i = 0; i < 8; ++i) { acc[i][0]=0.f; acc[i][1]=0.f; acc[i][2]=0.f; acc[i][3]=0.f; }

    for (int ci = 0; ci < 128; ++ci) {
        float iv[3][10];
        #pragma unroll
        for (int r = 0; r < 3; ++r) {
            int base = ((row + r)*10)*128 + ci;
            #pragma unroll
            for (int x = 0; x < 10; ++x) iv[r][x] = lds[base + x*128];
        }
        #pragma unroll
        for (int ky = 0; ky < 3; ++ky)
        #pragma unroll
        for (int kx = 0; kx < 3; ++kx) {
            const float4 w4 = *reinterpret_cast<const float4*>(w + (((ky*3+kx)*129 + ci)*128) + co);
            #pragma unroll
            for (int col = 0; col < 8; ++col) {
                float v = iv[ky][col+kx];
                acc[col][0] = fmaf(v, w4.x, acc[col][0]);
                acc[col][1] = fmaf(v, w4.y, acc[col][1]);
                acc[col][2] = fmaf(v, w4.z, acc[col][2]);
                acc[col][3] = fmaf(v, w4.w, acc[col][3]);
            }
        }
    }

    // t-channel (input channel 128, constant t inside the image, 0 in padding)
    const float tst = st[0] + cfrac * st[2];
    const int gy = ty + row;
    #pragma unroll
    for (int ky = 0; ky < 3; ++ky) {
        const int iy = gy + ky - 1;
        const bool okY = ((unsigned)iy < 32u);
        #pragma unroll
        for (int kx = 0; kx < 3; ++kx) {
            const float4 w4 = *reinterpret_cast<const float4*>(w + (((ky*3+kx)*129 + 128)*128) + co);
            #pragma unroll
            for (int col = 0; col < 8; ++col) {
                int ix = tx + col + kx - 1;
                float v = (okY && (unsigned)ix < 32u) ? tst : 0.0f;
                acc[col][0] = fmaf(v, w4.x, acc[col][0]);
                acc[col][1] = fmaf(v, w4.y, acc[col][1]);
                acc[col][2] = fmaf(v, w4.z, acc[col][2]);
                acc[col][3] = fmaf(v, w4.w, acc[col][3]);
            }
        }
    }

    const float4 b4 = *reinterpret_cast<const float4*>(bias + co);
    float* ob = out + (((size_t)b*1024 + (size_t)gy*32 + tx)*128 + co);
    #pragma unroll
    for (int col = 0; col < 8; ++col) {
        float4 r;
        r.x = fmaxf(acc[col][0] + b4.x, 0.f);
        r.y = fmaxf(acc[col][1] + b4.y, 0.f);
        r.z = fmaxf(acc[col][2] + b4.z, 0.f);
        r.w = fmaxf(acc[col][3] + b4.w, 0.f);
        *reinterpret_cast<float4*>(ob + col*128) = r;
    }
}

// o = y + dt_c * (ca*ka + cb*kb + ...)
template<int NK>
__global__ __launch_bounds__(256) void axpy_kernel(
    float* __restrict__ o, const float* __restrict__ y,
    const float* __restrict__ ka, const float* __restrict__ kb,
    const float* __restrict__ kc, const float* __restrict__ kd,
    const float* __restrict__ ke,
    float ca, float cb, float cc, float cd, float ce,
    const float* __restrict__ st)
{
    if (st[3] != 0.0f) return;
    const float dt = st[2];
    int stride = gridDim.x * blockDim.x;
    for (int i = blockIdx.x*blockDim.x + threadIdx.x; i < N4; i += stride) {
        float4 a = reinterpret_cast<const float4*>(ka)[i];
        float sx = ca*a.x, sy = ca*a.y, sz = ca*a.z, sw = ca*a.w;
        if (NK > 1) { float4 v = reinterpret_cast<const float4*>(kb)[i]; sx += cb*v.x; sy += cb*v.y; sz += cb*v.z; sw += cb*v.w; }
        if (NK > 2) { float4 v = reinterpret_cast<const float4*>(kc)[i]; sx += cc*v.x; sy += cc*v.y; sz += cc*v.z; sw += cc*v.w; }
        if (NK > 3) { float4 v = reinterpret_cast<const float4*>(kd)[i]; sx += cd*v.x; sy += cd*v.y; sz += cd*v.z; sw += cd*v.w; }
        if (NK > 4) { float4 v = reinterpret_cast<const float4*>(ke)[i]; sx += ce*v.x; sy += ce*v.y; sz += ce*v.z; sw += ce*v.w; }
        float4 yv = reinterpret_cast<const float4*>(y)[i];
        float4 r;
        r.x = yv.x + dt*sx; r.y = yv.y + dt*sy; r.z = yv.z + dt*sz; r.w = yv.w + dt*sw;
        reinterpret_cast<float4*>(o)[i] = r;
    }
}

__global__ __launch_bounds__(256) void err_reduce_kernel(
    const float* __restrict__ y,  const float* __restrict__ y5,
    const float* __restrict__ k1, const float* __restrict__ k3,
    const float* __restrict__ k4, const float* __restrict__ k5,
    const float* __restrict__ k6, const float* __restrict__ k7,
    const float* __restrict__ st, double* __restrict__ acc_slot)
{
    if (st[3] != 0.0f) return;
    const float dt = st[2];
    const float E1 = (float)(35.0/384.0 - 5179.0/57600.0);
    const float E3 = (float)(500.0/1113.0 - 7571.0/16695.0);
    const float E4 = (float)(125.0/192.0 - 393.0/640.0);
    const float E5 = (float)(-2187.0/6784.0 + 92097.0/339200.0);
    const float E6 = (float)(11.0/84.0 - 187.0/2100.0);
    const float E7 = (float)(-1.0/40.0);
    float lsum = 0.f;
    int stride = gridDim.x*blockDim.x;
    for (int i = blockIdx.x*blockDim.x + threadIdx.x; i < N4; i += stride) {
        float4 a = reinterpret_cast<const float4*>(k1)[i];
        float4 c = reinterpret_cast<const float4*>(k3)[i];
        float4 d = reinterpret_cast<const float4*>(k4)[i];
        float4 e = reinterpret_cast<const float4*>(k5)[i];
        float4 f = reinterpret_cast<const float4*>(k6)[i];
        float4 g = reinterpret_cast<const float4*>(k7)[i];
        float4 yv = reinterpret_cast<const float4*>(y)[i];
        float4 v5 = reinterpret_cast<const float4*>(y5)[i];
        {
            float err = dt*(E1*a.x + E3*c.x + E4*d.x + E5*e.x + E6*f.x + E7*g.x);
            float sc  = 1e-3f + 1e-3f*fmaxf(fabsf(yv.x), fabsf(v5.x));
            float r = err/sc; lsum += r*r;
        }
        {
            float err = dt*(E1*a.y + E3*c.y + E4*d.y + E5*e.y + E6*f.y + E7*g.y);
            float sc  = 1e-3f + 1e-3f*fmaxf(fabsf(yv.y), fabsf(v5.y));
            float r = err/sc; lsum += r*r;
        }
        {
            float err = dt*(E1*a.z + E3*c.z + E4*d.z + E5*e.z + E6*f.z + E7*g.z);
            float sc  = 1e-3f + 1e-3f*fmaxf(fabsf(yv.z), fabsf(v5.z));
            float r = err/sc; lsum += r*r;
        }
        {
            float err = dt*(E1*a.w + E3*c.w + E4*d.w + E5*e.w + E6*f.w + E7*g.w);
            float sc  = 1e-3f + 1e-3f*fmaxf(fabsf(yv.w), fabsf(v5.w));
            float r = err/sc; lsum += r*r;
        }
    }
    #pragma unroll
    for (int off = 32; off > 0; off >>= 1) lsum += __shfl_down(lsum, off, 64);
    __shared__ float ws_[4];
    int wid = threadIdx.x >> 6, lane = threadIdx.x & 63;
    if (lane == 0) ws_[wid] = lsum;
    __syncthreads();
    if (threadIdx.x == 0) {
        float bs = ws_[0] + ws_[1] + ws_[2] + ws_[3];
        atomicAdd(acc_slot, (double)bs);
    }
}

__global__ __launch_bounds__(64) void ctrl_kernel(float* __restrict__ st, const double* __restrict__ acc_slot)
{
    if (threadIdx.x != 0) return;
    float t = st[0], dt = st[1], dtc = st[2];
    bool done = (st[3] != 0.0f);
    float err_norm = sqrtf((float)(*acc_slot / (double)NTOT));
    err_norm = fmaxf(err_norm, 1e-10f);
    bool accept = (err_norm <= 1.0f);
    float factor = 0.9f * powf(err_norm, -0.2f);
    factor = fminf(fmaxf(factor, 0.2f), 10.0f);
    bool adv = accept && !done;
    if (adv) t = t + dtc;
    if (!done) dt = dtc * factor;
    done = done || (t >= 1.0f - 1e-6f);
    st[0] = t; st[1] = dt; st[3] = done ? 1.0f : 0.0f; st[4] = adv ? 1.0f : 0.0f;
    st[2] = fminf(dt, 1.0f - t);   // dt_c for next step
}

extern "C" void kernel_launch(void* const* d_in, const int* in_sizes, int n_in,
                              void* d_out, int out_size, void* d_ws, size_t ws_size,
                              hipStream_t stream)
{
    const float* x  = (const float*)d_in[0];
    const float* w1 = (const float*)d_in[1];
    const float* b1 = (const float*)d_in[2];
    const float* w2 = (const float*)d_in[3];
    const float* b2 = (const float*)d_in[4];

    char* ws = (char*)d_ws;
    double* acc = (double*)ws;                 // 32 doubles
    float*  st  = (float*)(ws + 256);          // scalar state
    float*  buf = (float*)(ws + 512);
    float* y  = buf + (size_t)NTOT*0;
    float* s  = buf + (size_t)NTOT*1;          // stage input / y5
    float* h  = buf + (size_t)NTOT*2;
    float* k1 = buf + (size_t)NTOT*3;
    float* k2 = buf + (size_t)NTOT*4;
    float* k3 = buf + (size_t)NTOT*5;
    float* k4 = buf + (size_t)NTOT*6;
    float* k5 = buf + (size_t)NTOT*7;
    float* k6 = buf + (size_t)NTOT*8;
    float* k7 = (float*)d_out;                 // reuse output buffer as k7 scratch

    const dim3 cgrid(16, NB);
    const dim3 cblk(256);
    const int ab = 1024;

    // Butcher tableau (f64-folded, cast to f32 like jnp)
    const float A21 = (float)(0.2);
    const float A31 = (float)(3.0/40.0),      A32 = (float)(9.0/40.0);
    const float A41 = (float)(44.0/45.0),     A42 = (float)(-56.0/15.0),    A43 = (float)(32.0/9.0);
    const float A51 = (float)(19372.0/6561.0),A52 = (float)(-25360.0/2187.0),A53 = (float)(64448.0/6561.0), A54 = (float)(-212.0/729.0);
    const float A61 = (float)(9017.0/3168.0), A62 = (float)(-355.0/33.0),   A63 = (float)(46732.0/5247.0), A64 = (float)(49.0/176.0), A65 = (float)(-5103.0/18656.0);
    const float B1  = (float)(35.0/384.0),    B3  = (float)(500.0/1113.0),  B4  = (float)(125.0/192.0),    B5  = (float)(-2187.0/6784.0), B6 = (float)(11.0/84.0);
    const float C2 = 0.2f, C3 = 0.3f, C4 = 0.8f, C5 = (float)(8.0/9.0);

    init_kernel<<<1, 64, 0, stream>>>(st, acc);
    copy_kernel<<<ab, 256, 0, stream>>>(y, x);

    for (int it = 0; it < 32; ++it) {
        // k1 = f(y, t)
        conv_relu_kernel<<<cgrid, cblk, 0, stream>>>(y, w1, b1, h, st, 0.0f);
        conv_relu_kernel<<<cgrid, cblk, 0, stream>>>(h, w2, b2, k1, st, 0.0f);
        // k2 = f(y + dt*0.2*k1, t + 0.2 dt)
        axpy_kernel<1><<<ab, 256, 0, stream>>>(s, y, k1, k1, k1, k1, k1, A21, 0,0,0,0, st);
        conv_relu_kernel<<<cgrid, cblk, 0, stream>>>(s, w1, b1, h, st, C2);
        conv_relu_kernel<<<cgrid, cblk, 0, stream>>>(h, w2, b2, k2, st, C2);
        // k3
        axpy_kernel<2><<<ab, 256, 0, stream>>>(s, y, k1, k2, k1, k1, k1, A31, A32, 0,0,0, st);
        conv_relu_kernel<<<cgrid, cblk, 0, stream>>>(s, w1, b1, h, st, C3);
        conv_relu_kernel<<<cgrid, cblk, 0, stream>>>(h, w2, b2, k3, st, C3);
        // k4
        axpy_kernel<3><<<ab, 256, 0, stream>>>(s, y, k1, k2, k3, k1, k1, A41, A42, A43, 0,0, st);
        conv_relu_kernel<<<cgrid, cblk, 0, stream>>>(s, w1, b1, h, st, C4);
        conv_relu_kernel<<<cgrid, cblk, 0, stream>>>(h, w2, b2, k4, st, C4);
        // k5
        axpy_kernel<4><<<ab, 256, 0, stream>>>(s, y, k1, k2, k3, k4, k1, A51, A52, A53, A54, 0, st);
        conv_relu_kernel<<<cgrid, cblk, 0, stream>>>(s, w1, b1, h, st, C5);
        conv_relu_kernel<<<cgrid, cblk, 0, stream>>>(h, w2, b2, k5, st, C5);
        // k6
        axpy_kernel<5><<<ab, 256, 0, stream>>>(s, y, k1, k2, k3, k4, k5, A61, A62, A63, A64, A65, st);
        conv_relu_kernel<<<cgrid, cblk, 0, stream>>>(s, w1, b1, h, st, 1.0f);
        conv_relu_kernel<<<cgrid, cblk, 0, stream>>>(h, w2, b2, k6, st, 1.0f);
        // y5 (into s) = y + dt*(B1 k1 + B3 k3 + B4 k4 + B5 k5 + B6 k6)
        axpy_kernel<5><<<ab, 256, 0, stream>>>(s, y, k1, k3, k4, k5, k6, B1, B3, B4, B5, B6, st);
        // k7 = f(y5, t + dt)
        conv_relu_kernel<<<cgrid, cblk, 0, stream>>>(s, w1, b1, h, st, 1.0f);
        conv_relu_kernel<<<cgrid, cblk, 0, stream>>>(h, w2, b2, k7, st, 1.0f);
        // error norm
        err_reduce_kernel<<<ab, 256, 0, stream>>>(y, s, k1, k3, k4, k5, k6, k7, st, acc + it);
        // controller
        ctrl_kernel<<<1, 64, 0, stream>>>(st, acc + it);
        // y = adv ? y5 : y
        copy_if_adv_kernel<<<ab, 256, 0, stream>>>(y, s, st);
    }

    copy_kernel<<<ab, 256, 0, stream>>>((float*)d_out, y);

    (void)in_sizes; (void)n_in; (void)out_size; (void)ws_size;
}

// Round 3
// 3020.924 us; speedup vs baseline: 2.2182x; 2.2182x over previous
//
#include <hip/hip_runtime.h>
#include <math.h>

#define NB    32
#define NHW   32
#define NC    128
#define NTOT  (NB*NHW*NHW*NC)     // 4194304
#define N4    (NTOT/4)
#define N8    (NTOT/8)
#define KDIM  1152                // 9 taps * 128 cin (t-channel handled in epilogue)

typedef unsigned short u16;
typedef __attribute__((ext_vector_type(8))) short short8v;   // 8 bf16 = 4 VGPR
typedef __attribute__((ext_vector_type(4))) float float4v;   // MFMA acc

__device__ inline float b2f(u16 u) { union { unsigned int i; float f; } x; x.i = ((unsigned int)u) << 16; return x.f; }
__device__ inline u16   f2b(float f) {
    union { unsigned int i; float f; } x; x.f = f;
    unsigned int u = x.i;
    return (u16)((u + 0x7fffu + ((u >> 16) & 1u)) >> 16);   // RNE, finite inputs
}
__device__ inline void ld8(const u16* __restrict__ p, float* v) {
    uint4 r = *(const uint4*)p;
    v[0] = b2f((u16)(r.x & 0xffff)); v[1] = b2f((u16)(r.x >> 16));
    v[2] = b2f((u16)(r.y & 0xffff)); v[3] = b2f((u16)(r.y >> 16));
    v[4] = b2f((u16)(r.z & 0xffff)); v[5] = b2f((u16)(r.z >> 16));
    v[6] = b2f((u16)(r.w & 0xffff)); v[7] = b2f((u16)(r.w >> 16));
}
__device__ inline uint4 pk8(const float* v) {
    uint4 o;
    o.x = (unsigned int)f2b(v[0]) | ((unsigned int)f2b(v[1]) << 16);
    o.y = (unsigned int)f2b(v[2]) | ((unsigned int)f2b(v[3]) << 16);
    o.z = (unsigned int)f2b(v[4]) | ((unsigned int)f2b(v[5]) << 16);
    o.w = (unsigned int)f2b(v[6]) | ((unsigned int)f2b(v[7]) << 16);
    return o;
}
__device__ inline void fma8(float* __restrict__ v, const u16* __restrict__ p, float s) {
    float kv[8];
    ld8(p, kv);
    #pragma unroll
    for (int j = 0; j < 8; ++j) v[j] = fmaf(s, kv[j], v[j]);
}

// state layout: st[0]=t, st[1]=dt, st[2]=dt_c, st[3]=done, st[4]=adv

__global__ __launch_bounds__(64) void init_kernel(float* __restrict__ st, double* __restrict__ acc)
{
    int i = threadIdx.x;
    if (i < 32) acc[i] = 0.0;
    if (i == 0) { st[0]=0.0f; st[1]=0.05f; st[2]=0.05f; st[3]=0.0f; st[4]=0.0f; }
}

// One-time weight transform: Wt[cout][tap*128+cin] bf16, Et[class][cout] f32
__global__ __launch_bounds__(256) void prep_kernel(
    const float* __restrict__ w, short* __restrict__ Wt, float* __restrict__ Et)
{
    const int part = blockIdx.x;  // 0..8 taps, 9 = E table
    const int tid = threadIdx.x;
    if (part < 9) {
        const int tap = part;
        for (int i = tid; i < 128*128; i += 256) {
            const int ci = i >> 7, co = i & 127;
            Wt[co*KDIM + tap*128 + ci] = (short)f2b(w[(tap*129 + ci)*128 + co]);
        }
    } else {
        for (int i = tid; i < 9*128; i += 256) {
            const int cls = i >> 7, co = i & 127;
            const int cy = cls / 3, cx = cls % 3;
            float s = 0.f;
            for (int ky = 0; ky < 3; ++ky) {
                if ((cy==0 && ky==0) || (cy==2 && ky==2)) continue;
                for (int kx = 0; kx < 3; ++kx) {
                    if ((cx==0 && kx==0) || (cx==2 && kx==2)) continue;
                    s += w[((ky*3+kx)*129 + 128)*128 + co];
                }
            }
            Et[cls*128 + co] = s;
        }
    }
}

__global__ __launch_bounds__(256) void copy_kernel(float* __restrict__ dst, const float* __restrict__ src)
{
    int stride = gridDim.x * blockDim.x;
    for (int i = blockIdx.x*blockDim.x + threadIdx.x; i < N4; i += stride)
        reinterpret_cast<float4*>(dst)[i] = reinterpret_cast<const float4*>(src)[i];
}

__global__ __launch_bounds__(256) void copy_if_adv_kernel(float* __restrict__ dst,
                                                          const float* __restrict__ src,
                                                          const float* __restrict__ st)
{
    if (st[4] == 0.0f) return;
    int stride = gridDim.x * blockDim.x;
    for (int i = blockIdx.x*blockDim.x + threadIdx.x; i < N4; i += stride)
        reinterpret_cast<float4*>(dst)[i] = reinterpret_cast<const float4*>(src)[i];
}

// ---------------------------------------------------------------------------
// MFMA implicit-GEMM conv 3x3 SAME, 128(+t)->128, bias+relu fused.
// Block: 16(y) x 8(x) spatial tile x 128 cout, one batch image. 4 waves in a
// 2x2 grid; each wave: 64 rows x 64 cout = 4x4 fragments of 16x16.
// Input patch staged in LDS as bf16 [180 pos][128 c] with XOR swizzle
// (byte ^= (pos&7)<<4) for conflict-free ds_read_b128 A-fragments.
// B = Wt[cout][K] bf16 from global (L1-resident, K-contiguous per lane).
// NK >= 0: input = basef(f32) + dt * sum(c_j * k_j(bf16))   [fused stage-axpy]
// NK == -1: input = bfin (bf16 direct)
// Epilogue adds bias + t * Et[boundary class] and applies ReLU; writes bf16.
// ---------------------------------------------------------------------------
template<int NK>
__global__ __launch_bounds__(256) void conv_mfma(
    const float* __restrict__ basef, const u16* __restrict__ bfin,
    const u16* __restrict__ ka, const u16* __restrict__ kb,
    const u16* __restrict__ kc, const u16* __restrict__ kd,
    const u16* __restrict__ ke,
    float ca, float cb, float cc2, float cd, float ce,
    const short* __restrict__ Wt, const float* __restrict__ bias,
    const float* __restrict__ Et,
    u16* __restrict__ out,
    const float* __restrict__ st, float cfrac)
{
    if (st[3] != 0.0f) return;
    __shared__ __align__(16) char lds[180*256];
    const int b    = blockIdx.y;
    const int tile = blockIdx.x;            // 0..7
    const int ty   = (tile >> 2) * 16;
    const int tx   = (tile & 3) * 8;
    const int tid  = threadIdx.x;
    const float dt = st[2];

    // ---- stage input patch (18x10 halo x 128c) to LDS as bf16 ----
    const size_t ibase = (size_t)b * (NHW*NHW*NC);
    for (int i = tid; i < 180*16; i += 256) {
        const int pos = i >> 4, cc = i & 15;
        const int sy = pos / 10, sx = pos - sy*10;
        const int gy = ty + sy - 1, gx = tx + sx - 1;
        const bool ok = ((unsigned)gy < 32u) && ((unsigned)gx < 32u);
        uint4 w128;
        if (!ok) {
            w128 = make_uint4(0u, 0u, 0u, 0u);
        } else if (NK < 0) {
            w128 = *(const uint4*)(bfin + ibase + (size_t)(gy*32 + gx)*128 + cc*8);
        } else {
            const size_t idx = ibase + (size_t)(gy*32 + gx)*128 + cc*8;
            float v[8];
            *(float4*)(v)     = *(const float4*)(basef + idx);
            *(float4*)(v + 4) = *(const float4*)(basef + idx + 4);
            if (NK >= 1) fma8(v, ka + idx, dt*ca);
            if (NK >= 2) fma8(v, kb + idx, dt*cb);
            if (NK >= 3) fma8(v, kc + idx, dt*cc2);
            if (NK >= 4) fma8(v, kd + idx, dt*cd);
            if (NK >= 5) fma8(v, ke + idx, dt*ce);
            w128 = pk8(v);
        }
        *(uint4*)(lds + pos*256 + ((cc*16) ^ ((pos & 7) << 4))) = w128;
    }
    __syncthreads();

    // ---- MFMA main loop ----
    const int l  = tid & 63;
    const int w  = tid >> 6;
    const int wy = w >> 1, wx = w & 1;     // 2x2 wave grid
    const int lr = l & 15,  kg = l >> 4;   // A-row / B-col lane index, k-subgroup

    float4v acc[4][4];
    #pragma unroll
    for (int ra = 0; ra < 4; ++ra)
        #pragma unroll
        for (int nb = 0; nb < 4; ++nb)
            acc[ra][nb] = (float4v){0.f, 0.f, 0.f, 0.f};

    int sy0[4], sx0[4];
    #pragma unroll
    for (int ra = 0; ra < 4; ++ra) {
        const int r = wy*64 + ra*16 + lr;
        sy0[ra] = r >> 3; sx0[ra] = r & 7;
    }

    #pragma unroll
    for (int ky = 0; ky < 3; ++ky) {
        #pragma unroll
        for (int kx = 0; kx < 3; ++kx) {
            const int tap = ky*3 + kx;
            #pragma unroll
            for (int kk = 0; kk < 4; ++kk) {
                short8v a[4], bb[4];
                const int cc = kk*4 + kg;
                #pragma unroll
                for (int ra = 0; ra < 4; ++ra) {
                    const int pos = (sy0[ra] + ky)*10 + sx0[ra] + kx;
                    a[ra] = *(const short8v*)(lds + pos*256 + ((cc*16) ^ ((pos & 7) << 4)));
                }
                const short* wb = Wt + tap*128 + kk*32 + kg*8;
                #pragma unroll
                for (int nb = 0; nb < 4; ++nb) {
                    const int cout = wx*64 + nb*16 + lr;
                    bb[nb] = *(const short8v*)(wb + (size_t)cout*KDIM);
                }
                #pragma unroll
                for (int ra = 0; ra < 4; ++ra)
                    #pragma unroll
                    for (int nb = 0; nb < 4; ++nb)
                        acc[ra][nb] = __builtin_amdgcn_mfma_f32_16x16x32_bf16(a[ra], bb[nb], acc[ra][nb], 0, 0, 0);
            }
        }
    }

    // ---- epilogue: + bias + t*E[class] , ReLU, store bf16 ----
    const float tval = st[0] + cfrac*dt;
    #pragma unroll
    for (int nb = 0; nb < 4; ++nb) {
        const int cout = wx*64 + nb*16 + lr;
        const float bsv = bias[cout];
        #pragma unroll
        for (int ra = 0; ra < 4; ++ra) {
            #pragma unroll
            for (int ri = 0; ri < 4; ++ri) {
                const int r  = wy*64 + ra*16 + kg*4 + ri;
                const int yy = ty + (r >> 3), xx = tx + (r & 7);
                const int cy = (yy == 0) ? 0 : ((yy == 31) ? 2 : 1);
                const int cx = (xx == 0) ? 0 : ((xx == 31) ? 2 : 1);
                float v = acc[ra][nb][ri] + bsv + tval*Et[(cy*3 + cx)*128 + cout];
                v = fmaxf(v, 0.f);
                out[(size_t)b*131072 + (size_t)(yy*32 + xx)*128 + cout] = f2b(v);
            }
        }
    }
}

// y5 = y + dt*(B1 k1 + B3 k3 + B4 k4 + B5 k5 + B6 k6)   (k's bf16, y/y5 f32)
__global__ __launch_bounds__(256) void axpy5_kernel(
    float* __restrict__ y5, const float* __restrict__ y,
    const u16* __restrict__ k1, const u16* __restrict__ k3,
    const u16* __restrict__ k4, const u16* __restrict__ k5,
    const u16* __restrict__ k6,
    float c1, float c3, float c4, float c5, float c6,
    const float* __restrict__ st)
{
    if (st[3] != 0.0f) return;
    const float dt = st[2];
    int stride = gridDim.x * blockDim.x;
    for (int i = blockIdx.x*blockDim.x + threadIdx.x; i < N8; i += stride) {
        const size_t base = (size_t)i * 8;
        float v[8];
        *(float4*)(v)     = *(const float4*)(y + base);
        *(float4*)(v + 4) = *(const float4*)(y + base + 4);
        fma8(v, k1 + base, dt*c1);
        fma8(v, k3 + base, dt*c3);
        fma8(v, k4 + base, dt*c4);
        fma8(v, k5 + base, dt*c5);
        fma8(v, k6 + base, dt*c6);
        *(float4*)(y5 + base)     = *(const float4*)(v);
        *(float4*)(y5 + base + 4) = *(const float4*)(v + 4);
    }
}

__global__ __launch_bounds__(256) void err_reduce_kernel(
    const float* __restrict__ y,  const float* __restrict__ y5,
    const u16* __restrict__ k1, const u16* __restrict__ k3,
    const u16* __restrict__ k4, const u16* __restrict__ k5,
    const u16* __restrict__ k6, const u16* __restrict__ k7,
    const float* __restrict__ st, double* __restrict__ acc_slot)
{
    if (st[3] != 0.0f) return;
    const float dt = st[2];
    const float E1 = (float)(35.0/384.0 - 5179.0/57600.0);
    const float E3 = (float)(500.0/1113.0 - 7571.0/16695.0);
    const float E4 = (float)(125.0/192.0 - 393.0/640.0);
    const float E5 = (float)(-2187.0/6784.0 + 92097.0/339200.0);
    const float E6 = (float)(11.0/84.0 - 187.0/2100.0);
    const float E7 = (float)(-1.0/40.0);
    float lsum = 0.f;
    int stride = gridDim.x*blockDim.x;
    for (int i = blockIdx.x*blockDim.x + threadIdx.x; i < N8; i += stride) {
        const size_t base = (size_t)i * 8;
        float a[8], c[8], d[8], e[8], f[8], g[8], yv[8], v5[8];
        ld8(k1 + base, a); ld8(k3 + base, c); ld8(k4 + base, d);
        ld8(k5 + base, e); ld8(k6 + base, f); ld8(k7 + base, g);
        *(float4*)(yv)     = *(const float4*)(y + base);
        *(float4*)(yv + 4) = *(const float4*)(y + base + 4);
        *(float4*)(v5)     = *(const float4*)(y5 + base);
        *(float4*)(v5 + 4) = *(const float4*)(y5 + base + 4);
        #pragma unroll
        for (int j = 0; j < 8; ++j) {
            float err = dt*(E1*a[j] + E3*c[j] + E4*d[j] + E5*e[j] + E6*f[j] + E7*g[j]);
            float sc  = 1e-3f + 1e-3f*fmaxf(fabsf(yv[j]), fabsf(v5[j]));
            float r = err/sc; lsum += r*r;
        }
    }
    #pragma unroll
    for (int off = 32; off > 0; off >>= 1) lsum += __shfl_down(lsum, off, 64);
    __shared__ float ws_[4];
    int wid = threadIdx.x >> 6, lane = threadIdx.x & 63;
    if (lane == 0) ws_[wid] = lsum;
    __syncthreads();
    if (threadIdx.x == 0) {
        float bs = ws_[0] + ws_[1] + ws_[2] + ws_[3];
        atomicAdd(acc_slot, (double)bs);
    }
}

__global__ __launch_bounds__(64) void ctrl_kernel(float* __restrict__ st, const double* __restrict__ acc_slot)
{
    if (threadIdx.x != 0) return;
    float t = st[0], dt = st[1], dtc = st[2];
    bool done = (st[3] != 0.0f);
    float err_norm = sqrtf((float)(*acc_slot / (double)NTOT));
    err_norm = fmaxf(err_norm, 1e-10f);
    bool accept = (err_norm <= 1.0f);
    float factor = 0.9f * powf(err_norm, -0.2f);
    factor = fminf(fmaxf(factor, 0.2f), 10.0f);
    bool adv = accept && !done;
    if (adv) t = t + dtc;
    if (!done) dt = dtc * factor;
    done = done || (t >= 1.0f - 1e-6f);
    st[0] = t; st[1] = dt; st[3] = done ? 1.0f : 0.0f; st[4] = adv ? 1.0f : 0.0f;
    st[2] = fminf(dt, 1.0f - t);
}

extern "C" void kernel_launch(void* const* d_in, const int* in_sizes, int n_in,
                              void* d_out, int out_size, void* d_ws, size_t ws_size,
                              hipStream_t stream)
{
    const float* x  = (const float*)d_in[0];
    const float* w1 = (const float*)d_in[1];
    const float* b1 = (const float*)d_in[2];
    const float* w2 = (const float*)d_in[3];
    const float* b2 = (const float*)d_in[4];

    char* ws = (char*)d_ws;
    double* acc = (double*)ws;                      // 32 doubles @ 0
    float*  st  = (float*)(ws + 256);
    float*  E1t = (float*)(ws + 512);               // 9*128 f32
    float*  E2t = (float*)(ws + 5120);
    short*  Wt1 = (short*)(ws + 10240);             // 128*1152 bf16 = 294912 B
    short*  Wt2 = (short*)(ws + 10240 + 294912);
    char*   bufs = ws + 1048576;                    // 1 MiB-aligned data region
    float* y  = (float*)(bufs);                     // 16 MiB
    float* y5 = (float*)(bufs + (size_t)NTOT*4);    // 16 MiB
    u16*   h  = (u16*)(bufs + (size_t)NTOT*8);      // bf16 buffers, 8 MiB each
    u16*   k1 = (u16*)(bufs + (size_t)NTOT*10);
    u16*   k2 = (u16*)(bufs + (size_t)NTOT*12);
    u16*   k3 = (u16*)(bufs + (size_t)NTOT*14);
    u16*   k4 = (u16*)(bufs + (size_t)NTOT*16);
    u16*   k5 = (u16*)(bufs + (size_t)NTOT*18);
    u16*   k6 = (u16*)(bufs + (size_t)NTOT*20);
    u16*   k7 = (u16*)(bufs + (size_t)NTOT*22);

    const dim3 cgrid(8, NB);     // 8 tiles (2y x 4x) * 32 batch = 256 blocks
    const dim3 cblk(256);
    const int ab = 2048;

    const float A21 = 0.2f;
    const float A31 = (float)(3.0/40.0),      A32 = (float)(9.0/40.0);
    const float A41 = (float)(44.0/45.0),     A42 = (float)(-56.0/15.0),     A43 = (float)(32.0/9.0);
    const float A51 = (float)(19372.0/6561.0),A52 = (float)(-25360.0/2187.0),A53 = (float)(64448.0/6561.0), A54 = (float)(-212.0/729.0);
    const float A61 = (float)(9017.0/3168.0), A62 = (float)(-355.0/33.0),    A63 = (float)(46732.0/5247.0), A64 = (float)(49.0/176.0), A65 = (float)(-5103.0/18656.0);
    const float B1  = (float)(35.0/384.0),    B3  = (float)(500.0/1113.0),   B4  = (float)(125.0/192.0),    B5  = (float)(-2187.0/6784.0), B6 = (float)(11.0/84.0);
    const float C2 = 0.2f, C3 = 0.3f, C4 = 0.8f, C5 = (float)(8.0/9.0);

    init_kernel<<<1, 64, 0, stream>>>(st, acc);
    prep_kernel<<<10, 256, 0, stream>>>(w1, Wt1, E1t);
    prep_kernel<<<10, 256, 0, stream>>>(w2, Wt2, E2t);
    copy_kernel<<<ab, 256, 0, stream>>>(y, x);

    for (int it = 0; it < 32; ++it) {
        // k1 = f(y, t)
        conv_mfma<0><<<cgrid, cblk, 0, stream>>>(y, h, k1,k1,k1,k1,k1, 0,0,0,0,0, Wt1, b1, E1t, h,  st, 0.0f);
        conv_mfma<-1><<<cgrid, cblk, 0, stream>>>(y, h, k1,k1,k1,k1,k1, 0,0,0,0,0, Wt2, b2, E2t, k1, st, 0.0f);
        // k2 = f(y + dt*0.2*k1, t+0.2dt)
        conv_mfma<1><<<cgrid, cblk, 0, stream>>>(y, h, k1,k1,k1,k1,k1, A21,0,0,0,0, Wt1, b1, E1t, h,  st, C2);
        conv_mfma<-1><<<cgrid, cblk, 0, stream>>>(y, h, k1,k1,k1,k1,k1, 0,0,0,0,0, Wt2, b2, E2t, k2, st, C2);
        // k3
        conv_mfma<2><<<cgrid, cblk, 0, stream>>>(y, h, k1,k2,k1,k1,k1, A31,A32,0,0,0, Wt1, b1, E1t, h,  st, C3);
        conv_mfma<-1><<<cgrid, cblk, 0, stream>>>(y, h, k1,k1,k1,k1,k1, 0,0,0,0,0, Wt2, b2, E2t, k3, st, C3);
        // k4
        conv_mfma<3><<<cgrid, cblk, 0, stream>>>(y, h, k1,k2,k3,k1,k1, A41,A42,A43,0,0, Wt1, b1, E1t, h,  st, C4);
        conv_mfma<-1><<<cgrid, cblk, 0, stream>>>(y, h, k1,k1,k1,k1,k1, 0,0,0,0,0, Wt2, b2, E2t, k4, st, C4);
        // k5
        conv_mfma<4><<<cgrid, cblk, 0, stream>>>(y, h, k1,k2,k3,k4,k1, A51,A52,A53,A54,0, Wt1, b1, E1t, h,  st, C5);
        conv_mfma<-1><<<cgrid, cblk, 0, stream>>>(y, h, k1,k1,k1,k1,k1, 0,0,0,0,0, Wt2, b2, E2t, k5, st, C5);
        // k6
        conv_mfma<5><<<cgrid, cblk, 0, stream>>>(y, h, k1,k2,k3,k4,k5, A61,A62,A63,A64,A65, Wt1, b1, E1t, h,  st, 1.0f);
        conv_mfma<-1><<<cgrid, cblk, 0, stream>>>(y, h, k1,k1,k1,k1,k1, 0,0,0,0,0, Wt2, b2, E2t, k6, st, 1.0f);
        // y5
        axpy5_kernel<<<ab, 256, 0, stream>>>(y5, y, k1, k3, k4, k5, k6, B1, B3, B4, B5, B6, st);
        // k7 = f(y5, t+dt)
        conv_mfma<0><<<cgrid, cblk, 0, stream>>>(y5, h, k1,k1,k1,k1,k1, 0,0,0,0,0, Wt1, b1, E1t, h,  st, 1.0f);
        conv_mfma<-1><<<cgrid, cblk, 0, stream>>>(y5, h, k1,k1,k1,k1,k1, 0,0,0,0,0, Wt2, b2, E2t, k7, st, 1.0f);
        // error + controller + accept
        err_reduce_kernel<<<ab, 256, 0, stream>>>(y, y5, k1, k3, k4, k5, k6, k7, st, acc + it);
        ctrl_kernel<<<1, 64, 0, stream>>>(st, acc + it);
        copy_if_adv_kernel<<<ab, 256, 0, stream>>>(y, y5, st);
    }

    copy_kernel<<<ab, 256, 0, stream>>>((float*)d_out, y);

    (void)in_sizes; (void)n_in; (void)out_size; (void)ws_size;
}